// Round 4
// baseline (219.421 us; speedup 1.0000x reference)
//
#include <hip/hip_runtime.h>
#include <hip/hip_bf16.h>

// Sizes fixed by the problem.
#define Bz 4
#define Nn 8192
#define Dd 512
#define Ll 64
#define Pp 128
#define Ww 64
#define Ss 32
#define NW 4   // number of window starts per segment

// ---------------------------------------------------------------------------
// fused init: zero accumulator region, seed out with bias, and (blocks 0..3)
// per-batch coord stats: mean + std(ddof=1)+1e-8 for x and y.
__global__ __launch_bounds__(256) void init_k(float* __restrict__ zbase, int nzero,
                                              float* __restrict__ out,
                                              const float* __restrict__ bo,
                                              const float* __restrict__ coords,
                                              float* __restrict__ cstats) {
    int i = blockIdx.x * 256 + threadIdx.x;
    if (i < nzero) zbase[i] = 0.f;
    if (i < Bz * Ll * Dd) out[i] = bo[i & (Dd - 1)];
    if (blockIdx.x < Bz) {
        int b = blockIdx.x;
        int tid = threadIdx.x;
        double sx = 0, sy = 0, sxx = 0, syy = 0;
        for (int j = tid; j < Nn; j += 256) {
            double x = coords[((size_t)b * Nn + j) * 2 + 0];
            double y = coords[((size_t)b * Nn + j) * 2 + 1];
            sx += x; sy += y; sxx += x * x; syy += y * y;
        }
        for (int o = 32; o > 0; o >>= 1) {
            sx  += __shfl_down(sx,  o); sy  += __shfl_down(sy,  o);
            sxx += __shfl_down(sxx, o); syy += __shfl_down(syy, o);
        }
        __shared__ double red[4][4];
        int wv = tid >> 6, lane = tid & 63;
        if (lane == 0) { red[wv][0] = sx; red[wv][1] = sy; red[wv][2] = sxx; red[wv][3] = syy; }
        __syncthreads();
        if (tid == 0) {
            double tx = 0, ty = 0, txx = 0, tyy = 0;
            for (int k = 0; k < 4; ++k) { tx += red[k][0]; ty += red[k][1]; txx += red[k][2]; tyy += red[k][3]; }
            const double N = (double)Nn;
            double mux = tx / N, muy = ty / N;
            double vx = (txx - N * mux * mux) / (N - 1.0);
            double vy = (tyy - N * muy * muy) / (N - 1.0);
            cstats[b * 4 + 0] = (float)mux;
            cstats[b * 4 + 1] = (float)muy;
            cstats[b * 4 + 2] = (float)sqrt(vx) + 1e-8f;
            cstats[b * 4 + 3] = (float)sqrt(vy) + 1e-8f;
        }
    }
}

// ---------------------------------------------------------------------------
// Split-K one-shot GEMM tile (one load round, 64x32 partial, atomicAdd).
// Optional dual-B and fused row-sum epilogue.
template <int BT>
__global__ __launch_bounds__(256) void gemmsk(
    const float* __restrict__ A,
    const float* __restrict__ B1, float* __restrict__ C1,
    const float* __restrict__ B2, float* __restrict__ C2,
    const float* __restrict__ rs_scale, float* __restrict__ rs_out,
    int N, int K, int KZ) {
    __shared__ float As[64][68];
    __shared__ float Bs[64][36];
    int tid = threadIdx.x;
    int n0 = blockIdx.x * 32;
    int m0 = blockIdx.y * 64;
    int kz = blockIdx.z;
    const float* B = B1; float* C = C1; float* rso = rs_out;
    if (kz >= KZ) { kz -= KZ; B = B2; C = C2; rso = nullptr; }
    int k0 = kz * 64;
    {
        int r = tid >> 4, c4 = (tid & 15) * 4;
#pragma unroll
        for (int i = 0; i < 4; ++i) {
            const float4 v = *(const float4*)&A[(size_t)(m0 + r + 16 * i) * K + k0 + c4];
            *(float4*)&As[r + 16 * i][c4] = v;
        }
    }
    if (BT) {
        int nr = tid >> 4, c4 = (tid & 15) * 4;
#pragma unroll
        for (int i = 0; i < 2; ++i) {
            int nn = nr + 16 * i;
            const float4 v = *(const float4*)&B[(size_t)(n0 + nn) * K + k0 + c4];
            Bs[c4 + 0][nn] = v.x; Bs[c4 + 1][nn] = v.y;
            Bs[c4 + 2][nn] = v.z; Bs[c4 + 3][nn] = v.w;
        }
    } else {
        int kr = tid >> 3, c4 = (tid & 7) * 4;
#pragma unroll
        for (int i = 0; i < 2; ++i) {
            int kk = kr + 32 * i;
            const float4 v = *(const float4*)&B[(size_t)(k0 + kk) * N + n0 + c4];
            *(float4*)&Bs[kk][c4] = v;
        }
    }
    __syncthreads();
    int tx = tid & 31, ty = tid >> 5;
    float acc[8] = {0.f, 0.f, 0.f, 0.f, 0.f, 0.f, 0.f, 0.f};
#pragma unroll 16
    for (int kk = 0; kk < 64; ++kk) {
        float bv = Bs[kk][tx];
#pragma unroll
        for (int i = 0; i < 8; ++i)
            acc[i] = fmaf(As[ty + 8 * i][kk], bv, acc[i]);
    }
#pragma unroll
    for (int i = 0; i < 8; ++i)
        atomicAdd(&C[(size_t)(m0 + ty + 8 * i) * N + n0 + tx], acc[i]);
    if (rso != nullptr) {
        float sc = (rs_scale != nullptr) ? rs_scale[n0 + tx] : 1.0f;
#pragma unroll
        for (int i = 0; i < 8; ++i) {
            float v = acc[i] * sc;
            for (int o = 16; o > 0; o >>= 1) v += __shfl_xor(v, o);
            if (tx == 0) atomicAdd(&rso[m0 + ty + 8 * i], v);
        }
    }
}

// ---------------------------------------------------------------------------
// per-row pass: mu, rs = 1/sqrt(var+eps), a = QK_l . f_row. One wave per row,
// 4 rows per block -> 8192 blocks (32 waves/CU). Streams feats once at HBM rate.
__global__ __launch_bounds__(256) void rowpass_k(const float* __restrict__ feats,
                                                 const float* __restrict__ QKm,
                                                 float4* __restrict__ rst) {
    int wv = threadIdx.x >> 6, lane = threadIdx.x & 63;
    int row = blockIdx.x * 4 + wv;
    int l = (row >> 7) & 63;
    const float4* fr = (const float4*)(feats + (size_t)row * Dd);
    const float4* qk = (const float4*)(QKm + (size_t)l * Dd);
    float4 v0 = fr[lane];
    float4 v1 = fr[lane + 64];
    float4 q0 = qk[lane];
    float4 q1 = qk[lane + 64];
    float s  = v0.x + v0.y + v0.z + v0.w + v1.x + v1.y + v1.z + v1.w;
    float ss = v0.x * v0.x + v0.y * v0.y + v0.z * v0.z + v0.w * v0.w
             + v1.x * v1.x + v1.y * v1.y + v1.z * v1.z + v1.w * v1.w;
    float a  = v0.x * q0.x + v0.y * q0.y + v0.z * q0.z + v0.w * q0.w
             + v1.x * q1.x + v1.y * q1.y + v1.z * q1.z + v1.w * q1.w;
    for (int o = 32; o > 0; o >>= 1) {
        s += __shfl_xor(s, o); ss += __shfl_xor(ss, o); a += __shfl_xor(a, o);
    }
    if (lane == 0) {
        float mu  = s * (1.f / (float)Dd);
        float var = ss * (1.f / (float)Dd) - mu * mu;
        rst[row] = make_float4(mu, 1.f / sqrtf(var + 1e-5f), a, 0.f);
    }
}

// ---------------------------------------------------------------------------
// per-(b,l): pos-bias + softmax over windows, combine per-row weights.
// Writes swt (x0.25 folded) and scalar offset.
__global__ __launch_bounds__(512) void winsoft_k(
    const float* __restrict__ coords, const float* __restrict__ cstats,
    const float4* __restrict__ rst,
    const float* __restrict__ Gm,
    const float* __restrict__ sqk, const float* __restrict__ qb2,
    const float* __restrict__ W1, const float* __restrict__ b1,
    float* __restrict__ swt_g, float* __restrict__ soff_g) {
    __shared__ float4 wpack[Dd];            // {w1a, w1b, b1, g}
    __shared__ float  scx[Pp], scy[Pp];
    __shared__ float  smu[Pp], srs[Pp], sa[Pp];
    __shared__ float  shs[NW * Ww];
    __shared__ float  sar[NW][Ww];
    __shared__ float  scm[8];               // cmx[4], cmy[4]
    __shared__ float  s2red[NW];

    int bx = blockIdx.x;                    // b*64 + l
    int l = bx & 63, b = bx >> 6;
    int tid = threadIdx.x;
    int wv = tid >> 6, lane = tid & 63;

    wpack[tid] = make_float4(W1[2 * tid], W1[2 * tid + 1], b1[tid], Gm[l * Dd + tid]);
    if (tid < Pp) {
        int row = bx * Pp + tid;
        float x = coords[(size_t)row * 2], y = coords[(size_t)row * 2 + 1];
        scx[tid] = (x - cstats[b * 4 + 0]) / cstats[b * 4 + 2];
        scy[tid] = (y - cstats[b * 4 + 1]) / cstats[b * 4 + 3];
        float4 st = rst[row];
        smu[tid] = st.x; srs[tid] = st.y; sa[tid] = st.z;
    }
    float sqk_l = sqk[l], qb2_l = qb2[l];
    __syncthreads();

    // window coord means (waves 0..3)
    if (wv < 4) {
        int n = wv, w = lane;
        int nv = (n == 3) ? 32 : 64;
        float cx = (w < nv) ? scx[n * Ss + w] : 0.f;
        float cy = (w < nv) ? scy[n * Ss + w] : 0.f;
        for (int o = 32; o > 0; o >>= 1) { cx += __shfl_xor(cx, o); cy += __shfl_xor(cy, o); }
        if (lane == 0) { scm[n] = cx / (float)nv; scm[4 + n] = cy / (float)nv; }
    }
    __syncthreads();

    // pos-bias hs per (window, slot): 2 lanes per slot, half-D each
    {
        int s = tid >> 1, half = tid & 1;
        int n = s >> 6, w = s & 63;
        int nv = (n == 3) ? 32 : 64;
        float hs = 0.f;
        if (w < nv) {
            int p = n * Ss + w;
            float px = scx[p] - scm[n], py = scy[p] - scm[4 + n];
            int d0 = half * 256;
#pragma unroll 4
            for (int d = d0; d < d0 + 256; ++d) {
                float4 c = wpack[d];
                hs = fmaf(c.w, fmaxf(fmaf(c.x, px, fmaf(c.y, py, c.z)), 0.f), hs);
            }
        }
        hs += __shfl_xor(hs, 1);
        if (half == 0) shs[s] = hs;
    }
    __syncthreads();

    // softmax per window (waves 0..3)
    const float invtemp = 0.04419417382415922f; // 1/sqrt(512)
    if (wv < 4) {
        int n = wv, w = lane;
        int nv = (n == 3) ? 32 : 64;
        int p = n * Ss + ((w < nv) ? w : 0);
        float lg = -1e30f;
        if (w < nv) {
            lg = (srs[p] * (sa[p] - smu[p] * sqk_l) + shs[n * Ww + w] + qb2_l) * invtemp;
            lg = fminf(fmaxf(lg, -10.f), 10.f);
        }
        float m = lg;
        for (int o = 32; o > 0; o >>= 1) m = fmaxf(m, __shfl_xor(m, o));
        float e = (w < nv) ? expf(lg - m) : 0.f;
        float ssum = e;
        for (int o = 32; o > 0; o >>= 1) ssum += __shfl_xor(ssum, o);
        float ar = (w < nv) ? (e / ssum) * srs[p] : 0.f;
        sar[n][w] = ar;
        float t2 = (w < nv) ? ar * smu[p] : 0.f;
        for (int o = 32; o > 0; o >>= 1) t2 += __shfl_xor(t2, o);
        if (lane == 0) s2red[n] = t2;
    }
    __syncthreads();

    // combine per-row weights across (<=2) covering windows; x0.25 folded
    if (tid < Pp) {
        int p = tid;
        int na = (p >> 5) - 1, nb = (p >> 5);
        float wt = 0.f;
        if (na >= 0 && na <= 3) wt += sar[na][p - na * Ss];
        if (nb <= 3)            wt += sar[nb][p - nb * Ss];
        swt_g[bx * Pp + p] = 0.25f * wt;
    }
    if (tid == 0)
        soff_g[bx] = 0.25f * (s2red[0] + s2red[1] + s2red[2] + s2red[3]);
}

// ---------------------------------------------------------------------------
// weighted feature sum: fmean[bx][d] += sum_{p in quarter} swt[p]*f[p,d]
// (block 0 of each bx also subtracts the scalar offset). 1024 blocks.
__global__ __launch_bounds__(512) void wsum_k(const float* __restrict__ feats,
                                              const float* __restrict__ swt_g,
                                              const float* __restrict__ soff_g,
                                              float* __restrict__ fmean) {
    __shared__ float w_s[32];
    int bx = blockIdx.x >> 2, qtr = blockIdx.x & 3;
    int tid = threadIdx.x;
    if (tid < 32) w_s[tid] = swt_g[bx * Pp + qtr * 32 + tid];
    __syncthreads();
    const float* fbase = feats + ((size_t)bx * Pp + qtr * 32) * Dd;
    float acc = (qtr == 0 && soff_g) ? -soff_g[bx] : 0.f;
#pragma unroll 8
    for (int p = 0; p < 32; ++p)
        acc = fmaf(w_s[p], fbase[(size_t)p * Dd + tid], acc);
    atomicAdd(&fmean[(size_t)bx * Dd + tid], acc);
}

// ---------------------------------------------------------------------------
extern "C" void kernel_launch(void* const* d_in, const int* in_sizes, int n_in,
                              void* d_out, int out_size, void* d_ws, size_t ws_size,
                              hipStream_t stream) {
    const float* feats  = (const float*)d_in[0];
    const float* coords = (const float*)d_in[1];
    // d_in[2] = mask, unused (all false, and unused by the reference body)
    const float* z  = (const float*)d_in[3];
    const float* Wq = (const float*)d_in[4];
    const float* Wk = (const float*)d_in[5];
    const float* Wv = (const float*)d_in[6];
    const float* W1 = (const float*)d_in[7];
    const float* b1 = (const float*)d_in[8];
    const float* W2 = (const float*)d_in[9];
    const float* b2 = (const float*)d_in[10];
    const float* Wo = (const float*)d_in[11];
    const float* bo = (const float*)d_in[12];
    float* out = (float*)d_out;

    // workspace layout (floats)
    float* ws = (float*)d_ws;
    float*  cstats = ws;                        // 16
    float*  zbase  = ws + 16;                   // zero-init region:
    float*  Q      = zbase;                     // 64*512
    float*  QK     = Q + Ll * Dd;               // 64*512
    float*  G      = QK + Ll * Dd;              // 64*512
    float*  sqk    = G + Ll * Dd;               // 64
    float*  qb2    = sqk + Ll;                  // 64
    float*  zl     = qb2 + Ll;                  // 256*512
    float*  fmean  = zl + Bz * Ll * Dd;         // 256*512
    const int nzero = 3 * Ll * Dd + 2 * Ll + 2 * Bz * Ll * Dd;  // 360576
    float4* rst    = (float4*)(zbase + nzero);  // 32768 float4
    float*  swt_g  = zbase + nzero + 4 * Bz * Nn;  // 256*128
    float*  soff_g = swt_g + Bz * Ll * Pp;      // 256

    init_k<<<(nzero + 255) / 256, 256, 0, stream>>>(zbase, nzero, out, bo, coords, cstats);

    // Q = z @ Wq^T (split-K); epilogue: qb2[l] = sum_e Q[l,e]*b2[e]
    gemmsk<1><<<dim3(Dd / 32, Ll / 64, 8), 256, 0, stream>>>(
        z, Wq, Q, nullptr, nullptr, b2, qb2, Dd, Dd, 8);
    // QK = Q @ Wk and G = Q @ W2 fused; epilogue: sqk[l] = sum_d QK[l,d]
    gemmsk<0><<<dim3(Dd / 32, Ll / 64, 16), 256, 0, stream>>>(
        Q, Wk, QK, W2, G, nullptr, sqk, Dd, Dd, 8);

    rowpass_k<<<Bz * Nn / 4, 256, 0, stream>>>(feats, QK, rst);
    winsoft_k<<<Bz * Ll, 512, 0, stream>>>(coords, cstats, rst, G, sqk, qb2,
                                           W1, b1, swt_g, soff_g);
    wsum_k<<<Bz * Ll * 4, 512, 0, stream>>>(feats, swt_g, soff_g, fmean);

    // zl = fmean @ Wv^T ; out = bias + zl @ Wo^T
    gemmsk<1><<<dim3(Dd / 32, (Bz * Ll) / 64, 8), 256, 0, stream>>>(
        fmean, Wv, zl, nullptr, nullptr, nullptr, nullptr, Dd, Dd, 8);
    gemmsk<1><<<dim3(Dd / 32, (Bz * Ll) / 64, 8), 256, 0, stream>>>(
        zl, Wo, out, nullptr, nullptr, nullptr, nullptr, Dd, Dd, 8);
}

// Round 5
// 216.963 us; speedup vs baseline: 1.0113x; 1.0113x over previous
//
#include <hip/hip_runtime.h>
#include <hip/hip_bf16.h>

// Sizes fixed by the problem.
#define Bz 4
#define Nn 8192
#define Dd 512
#define Ll 64
#define Pp 128
#define Ww 64
#define Ss 32
#define NW 4   // number of window starts per segment

// ---------------------------------------------------------------------------
// fused init: zero accumulator region, seed out with bias, and (blocks 0..3)
// per-batch coord stats: mean + std(ddof=1)+1e-8 for x and y.
__global__ __launch_bounds__(256) void init_k(float* __restrict__ zbase, int nzero,
                                              float* __restrict__ out,
                                              const float* __restrict__ bo,
                                              const float* __restrict__ coords,
                                              float* __restrict__ cstats) {
    int i = blockIdx.x * 256 + threadIdx.x;
    if (i < nzero) zbase[i] = 0.f;
    if (i < Bz * Ll * Dd) out[i] = bo[i & (Dd - 1)];
    if (blockIdx.x < Bz) {
        int b = blockIdx.x;
        int tid = threadIdx.x;
        double sx = 0, sy = 0, sxx = 0, syy = 0;
        for (int j = tid; j < Nn; j += 256) {
            double x = coords[((size_t)b * Nn + j) * 2 + 0];
            double y = coords[((size_t)b * Nn + j) * 2 + 1];
            sx += x; sy += y; sxx += x * x; syy += y * y;
        }
        for (int o = 32; o > 0; o >>= 1) {
            sx  += __shfl_down(sx,  o); sy  += __shfl_down(sy,  o);
            sxx += __shfl_down(sxx, o); syy += __shfl_down(syy, o);
        }
        __shared__ double red[4][4];
        int wv = tid >> 6, lane = tid & 63;
        if (lane == 0) { red[wv][0] = sx; red[wv][1] = sy; red[wv][2] = sxx; red[wv][3] = syy; }
        __syncthreads();
        if (tid == 0) {
            double tx = 0, ty = 0, txx = 0, tyy = 0;
            for (int k = 0; k < 4; ++k) { tx += red[k][0]; ty += red[k][1]; txx += red[k][2]; tyy += red[k][3]; }
            const double N = (double)Nn;
            double mux = tx / N, muy = ty / N;
            double vx = (txx - N * mux * mux) / (N - 1.0);
            double vy = (tyy - N * muy * muy) / (N - 1.0);
            cstats[b * 4 + 0] = (float)mux;
            cstats[b * 4 + 1] = (float)muy;
            cstats[b * 4 + 2] = (float)sqrt(vx) + 1e-8f;
            cstats[b * 4 + 3] = (float)sqrt(vy) + 1e-8f;
        }
    }
}

// ---------------------------------------------------------------------------
// Split-K one-shot GEMM tile (one load round, 64x32 partial, atomicAdd).
// Optional dual-B and fused row-sum epilogue.
template <int BT>
__global__ __launch_bounds__(256) void gemmsk(
    const float* __restrict__ A,
    const float* __restrict__ B1, float* __restrict__ C1,
    const float* __restrict__ B2, float* __restrict__ C2,
    const float* __restrict__ rs_scale, float* __restrict__ rs_out,
    int N, int K, int KZ) {
    __shared__ float As[64][68];
    __shared__ float Bs[64][36];
    int tid = threadIdx.x;
    int n0 = blockIdx.x * 32;
    int m0 = blockIdx.y * 64;
    int kz = blockIdx.z;
    const float* B = B1; float* C = C1; float* rso = rs_out;
    if (kz >= KZ) { kz -= KZ; B = B2; C = C2; rso = nullptr; }
    int k0 = kz * 64;
    {
        int r = tid >> 4, c4 = (tid & 15) * 4;
#pragma unroll
        for (int i = 0; i < 4; ++i) {
            const float4 v = *(const float4*)&A[(size_t)(m0 + r + 16 * i) * K + k0 + c4];
            *(float4*)&As[r + 16 * i][c4] = v;
        }
    }
    if (BT) {
        int nr = tid >> 4, c4 = (tid & 15) * 4;
#pragma unroll
        for (int i = 0; i < 2; ++i) {
            int nn = nr + 16 * i;
            const float4 v = *(const float4*)&B[(size_t)(n0 + nn) * K + k0 + c4];
            Bs[c4 + 0][nn] = v.x; Bs[c4 + 1][nn] = v.y;
            Bs[c4 + 2][nn] = v.z; Bs[c4 + 3][nn] = v.w;
        }
    } else {
        int kr = tid >> 3, c4 = (tid & 7) * 4;
#pragma unroll
        for (int i = 0; i < 2; ++i) {
            int kk = kr + 32 * i;
            const float4 v = *(const float4*)&B[(size_t)(k0 + kk) * N + n0 + c4];
            *(float4*)&Bs[kk][c4] = v;
        }
    }
    __syncthreads();
    int tx = tid & 31, ty = tid >> 5;
    float acc[8] = {0.f, 0.f, 0.f, 0.f, 0.f, 0.f, 0.f, 0.f};
#pragma unroll 16
    for (int kk = 0; kk < 64; ++kk) {
        float bv = Bs[kk][tx];
#pragma unroll
        for (int i = 0; i < 8; ++i)
            acc[i] = fmaf(As[ty + 8 * i][kk], bv, acc[i]);
    }
#pragma unroll
    for (int i = 0; i < 8; ++i)
        atomicAdd(&C[(size_t)(m0 + ty + 8 * i) * N + n0 + tx], acc[i]);
    if (rso != nullptr) {
        float sc = (rs_scale != nullptr) ? rs_scale[n0 + tx] : 1.0f;
#pragma unroll
        for (int i = 0; i < 8; ++i) {
            float v = acc[i] * sc;
            for (int o = 16; o > 0; o >>= 1) v += __shfl_xor(v, o);
            if (tx == 0) atomicAdd(&rso[m0 + ty + 8 * i], v);
        }
    }
}

// ---------------------------------------------------------------------------
// Fused attention, one block per (b,l), 512 threads.
// Pass 1: per-row (mu, rs, a=QK_l.f) with 4 rows concurrent per wave
//   (16 lanes/row, 8 independent float4 loads each -> deep MLP).
// Middle: window coord means, pos-bias, softmax, weight combine (LDS only).
// Pass 2: combined weighted feature sum, direct store (no atomics).
__global__ __launch_bounds__(512) void attn3(
    const float* __restrict__ feats, const float* __restrict__ coords,
    const float* __restrict__ cstats,
    const float* __restrict__ QKm, const float* __restrict__ Gm,
    const float* __restrict__ sqk, const float* __restrict__ qb2,
    const float* __restrict__ W1, const float* __restrict__ b1,
    float* __restrict__ fmean) {
    __shared__ float  qk_s[Dd];
    __shared__ float4 wpack[Dd];            // {w1a, w1b, b1, g}
    __shared__ float  scx[Pp], scy[Pp];
    __shared__ float  smu[Pp], srs[Pp], sa[Pp];
    __shared__ float  shs[NW * Ww];
    __shared__ float  sar[NW][Ww];
    __shared__ float  swt[Pp];
    __shared__ float  scm[8];               // cmx[4], cmy[4]
    __shared__ float  s2red[NW];
    __shared__ float  soff_s;

    int bx = blockIdx.x;                    // b*64 + l
    int l = bx & 63, b = bx >> 6;
    int tid = threadIdx.x;
    int wv = tid >> 6, lane = tid & 63;

    // ---- prologue ----
    qk_s[tid]  = QKm[l * Dd + tid];
    wpack[tid] = make_float4(W1[2 * tid], W1[2 * tid + 1], b1[tid], Gm[l * Dd + tid]);
    if (tid < Pp) {
        int row = bx * Pp + tid;
        float x = coords[(size_t)row * 2], y = coords[(size_t)row * 2 + 1];
        scx[tid] = (x - cstats[b * 4 + 0]) / cstats[b * 4 + 2];
        scy[tid] = (y - cstats[b * 4 + 1]) / cstats[b * 4 + 3];
    }
    float sqk_l = sqk[l], qb2_l = qb2[l];
    __syncthreads();

    // ---- pass 1: wave wv covers rows wv*16..wv*16+15, 4 rows at a time ----
    const float*  fbase = feats + (size_t)bx * Pp * Dd;
    const float4* f4    = (const float4*)fbase;
    const float4* q4    = (const float4*)qk_s;
    int sub = lane >> 4, g = lane & 15;     // row-in-group, float4 group index
#pragma unroll
    for (int i = 0; i < 4; ++i) {
        int r = wv * 16 + i * 4 + sub;
        float s = 0.f, ss = 0.f, a = 0.f;
#pragma unroll
        for (int j = 0; j < 8; ++j) {
            float4 v = f4[r * 128 + g + 16 * j];
            float4 q = q4[g + 16 * j];
            s  += v.x + v.y + v.z + v.w;
            ss += v.x * v.x + v.y * v.y + v.z * v.z + v.w * v.w;
            a  += v.x * q.x + v.y * q.y + v.z * q.z + v.w * q.w;
        }
        for (int o = 8; o > 0; o >>= 1) {
            s  += __shfl_xor(s,  o, 16);
            ss += __shfl_xor(ss, o, 16);
            a  += __shfl_xor(a,  o, 16);
        }
        if (g == 0) {
            float mu  = s * (1.f / (float)Dd);
            float var = ss * (1.f / (float)Dd) - mu * mu;
            smu[r] = mu; srs[r] = 1.f / sqrtf(var + 1e-5f); sa[r] = a;
        }
    }
    __syncthreads();

    // ---- window coord means (waves 0..3) ----
    if (wv < 4) {
        int n = wv, w = lane;
        int nv = (n == 3) ? 32 : 64;
        float cx = (w < nv) ? scx[n * Ss + w] : 0.f;
        float cy = (w < nv) ? scy[n * Ss + w] : 0.f;
        for (int o = 32; o > 0; o >>= 1) { cx += __shfl_xor(cx, o); cy += __shfl_xor(cy, o); }
        if (lane == 0) { scm[n] = cx / (float)nv; scm[4 + n] = cy / (float)nv; }
    }
    __syncthreads();

    // ---- pos-bias hs per (window, slot): 2 lanes per slot, half-D each ----
    {
        int s = tid >> 1, half = tid & 1;
        int n = s >> 6, w = s & 63;
        int nv = (n == 3) ? 32 : 64;
        float hs = 0.f;
        if (w < nv) {
            int p = n * Ss + w;
            float px = scx[p] - scm[n], py = scy[p] - scm[4 + n];
            int d0 = half * 256;
#pragma unroll 4
            for (int d = d0; d < d0 + 256; ++d) {
                float4 c = wpack[d];
                hs = fmaf(c.w, fmaxf(fmaf(c.x, px, fmaf(c.y, py, c.z)), 0.f), hs);
            }
        }
        hs += __shfl_xor(hs, 1);
        if (half == 0) shs[s] = hs;
    }
    __syncthreads();

    // ---- softmax per window (waves 0..3) ----
    const float invtemp = 0.04419417382415922f; // 1/sqrt(512)
    if (wv < 4) {
        int n = wv, w = lane;
        int nv = (n == 3) ? 32 : 64;
        int p = n * Ss + ((w < nv) ? w : 0);
        float lg = -1e30f;
        if (w < nv) {
            lg = (srs[p] * (sa[p] - smu[p] * sqk_l) + shs[n * Ww + w] + qb2_l) * invtemp;
            lg = fminf(fmaxf(lg, -10.f), 10.f);
        }
        float m = lg;
        for (int o = 32; o > 0; o >>= 1) m = fmaxf(m, __shfl_xor(m, o));
        float e = (w < nv) ? expf(lg - m) : 0.f;
        float ssum = e;
        for (int o = 32; o > 0; o >>= 1) ssum += __shfl_xor(ssum, o);
        float ar = (w < nv) ? (e / ssum) * srs[p] : 0.f;
        sar[n][w] = ar;
        float t2 = (w < nv) ? ar * smu[p] : 0.f;
        for (int o = 32; o > 0; o >>= 1) t2 += __shfl_xor(t2, o);
        if (lane == 0) s2red[n] = t2;
    }
    __syncthreads();

    // ---- combine per-row weights (<=2 covering windows); x0.25 folded ----
    if (tid < Pp) {
        int p = tid;
        int na = (p >> 5) - 1, nb = (p >> 5);
        float wt = 0.f;
        if (na >= 0 && na <= 3) wt += sar[na][p - na * Ss];
        if (nb <= 3)            wt += sar[nb][p - nb * Ss];
        swt[p] = 0.25f * wt;
    }
    if (tid == 0)
        soff_s = 0.25f * (s2red[0] + s2red[1] + s2red[2] + s2red[3]);
    __syncthreads();

    // ---- pass 2: weighted feature sum over 128 rows (L2-warm), direct store --
    {
        int c = tid;
        float a0 = 0.f, a1 = 0.f, a2 = 0.f, a3 = 0.f;
#pragma unroll 8
        for (int p = 0; p < Pp; p += 4) {
            a0 = fmaf(swt[p + 0], fbase[(size_t)(p + 0) * Dd + c], a0);
            a1 = fmaf(swt[p + 1], fbase[(size_t)(p + 1) * Dd + c], a1);
            a2 = fmaf(swt[p + 2], fbase[(size_t)(p + 2) * Dd + c], a2);
            a3 = fmaf(swt[p + 3], fbase[(size_t)(p + 3) * Dd + c], a3);
        }
        fmean[(size_t)bx * Dd + c] = (a0 + a1) + (a2 + a3) - soff_s;
    }
}

// ---------------------------------------------------------------------------
extern "C" void kernel_launch(void* const* d_in, const int* in_sizes, int n_in,
                              void* d_out, int out_size, void* d_ws, size_t ws_size,
                              hipStream_t stream) {
    const float* feats  = (const float*)d_in[0];
    const float* coords = (const float*)d_in[1];
    // d_in[2] = mask, unused (all false, and unused by the reference body)
    const float* z  = (const float*)d_in[3];
    const float* Wq = (const float*)d_in[4];
    const float* Wk = (const float*)d_in[5];
    const float* Wv = (const float*)d_in[6];
    const float* W1 = (const float*)d_in[7];
    const float* b1 = (const float*)d_in[8];
    const float* W2 = (const float*)d_in[9];
    const float* b2 = (const float*)d_in[10];
    const float* Wo = (const float*)d_in[11];
    const float* bo = (const float*)d_in[12];
    float* out = (float*)d_out;

    // workspace layout (floats)
    float* ws = (float*)d_ws;
    float*  cstats = ws;                        // 16
    float*  zbase  = ws + 16;                   // zero-init region:
    float*  Q      = zbase;                     // 64*512
    float*  QK     = Q + Ll * Dd;               // 64*512
    float*  G      = QK + Ll * Dd;              // 64*512
    float*  sqk    = G + Ll * Dd;               // 64
    float*  qb2    = sqk + Ll;                  // 64
    float*  zl     = qb2 + Ll;                  // 256*512
    const int nzero = 3 * Ll * Dd + 2 * Ll + Bz * Ll * Dd;  // 229504
    float*  fmean  = zbase + nzero;             // 256*512 (written directly)

    init_k<<<(nzero + 255) / 256, 256, 0, stream>>>(zbase, nzero, out, bo, coords, cstats);

    // Q = z @ Wq^T (split-K); epilogue: qb2[l] = sum_e Q[l,e]*b2[e]
    gemmsk<1><<<dim3(Dd / 32, Ll / 64, 8), 256, 0, stream>>>(
        z, Wq, Q, nullptr, nullptr, b2, qb2, Dd, Dd, 8);
    // QK = Q @ Wk and G = Q @ W2 fused; epilogue: sqk[l] = sum_d QK[l,d]
    gemmsk<0><<<dim3(Dd / 32, Ll / 64, 16), 256, 0, stream>>>(
        Q, Wk, QK, W2, G, nullptr, sqk, Dd, Dd, 8);

    attn3<<<Bz * Ll, 512, 0, stream>>>(feats, coords, cstats,
                                       QK, G, sqk, qb2, W1, b1, fmean);

    // zl = fmean @ Wv^T ; out = bias + zl @ Wo^T
    gemmsk<1><<<dim3(Dd / 32, (Bz * Ll) / 64, 8), 256, 0, stream>>>(
        fmean, Wv, zl, nullptr, nullptr, nullptr, nullptr, Dd, Dd, 8);
    gemmsk<1><<<dim3(Dd / 32, (Bz * Ll) / 64, 8), 256, 0, stream>>>(
        zl, Wo, out, nullptr, nullptr, nullptr, nullptr, Dd, Dd, 8);
}